// Round 16
// baseline (6203.663 us; speedup 1.0000x reference)
//
#include <hip/hip_runtime.h>
#include <stdint.h>
#include <math.h>

#define NW      4096
#define TSTEPS  5722     // BURNIN + (512-1)*11 + 1
#define BURN    100
#define SSTRIDE 11
#define NTHR    256
#define NBOUND  522      // 10 windows(10) + 1 window(1 @t=100) + 511 windows(11)

struct K2 { uint32_t a, b; };

// Threefry-2x32, 20 rounds — matches jax._src.prng.threefry2x32 exactly.
__device__ __forceinline__ K2 tf(uint32_t k0, uint32_t k1, uint32_t c0, uint32_t c1) {
  uint32_t ks2 = k0 ^ k1 ^ 0x1BD11BDAu;
  uint32_t x0 = c0 + k0, x1 = c1 + k1;
#define RR(r) { x0 += x1; x1 = (x1 << (r)) | (x1 >> (32 - (r))); x1 ^= x0; }
  RR(13) RR(15) RR(26) RR(6)
  x0 += k1;  x1 += ks2 + 1u;
  RR(17) RR(29) RR(16) RR(24)
  x0 += ks2; x1 += k0 + 2u;
  RR(13) RR(15) RR(26) RR(6)
  x0 += k0;  x1 += k1 + 3u;
  RR(17) RR(29) RR(16) RR(24)
  x0 += k1;  x1 += ks2 + 4u;
  RR(13) RR(15) RR(26) RR(6)
  x0 += ks2; x1 += k0 + 5u;
#undef RR
  K2 r; r.a = x0; r.b = x1; return r;
}

__device__ __forceinline__ uint32_t xbits(K2 k) {
  K2 r = tf(k.a, k.b, 0u, 0u);
  return r.a ^ r.b;
}

__device__ __forceinline__ uint32_t ri_off(K2 key, uint32_t span) {
  K2 k1 = tf(key.a, key.b, 0u, 0u);
  K2 k2 = tf(key.a, key.b, 0u, 1u);
  uint32_t hb = xbits(k1);
  uint32_t lb = xbits(k2);
  uint32_t m = 65536u % span;
  m = (m * m) % span;
  return ((hb % span) * m + (lb % span)) % span;
}

__device__ __noinline__ void make_prop(uint32_t kca, uint32_t kcb, int t,
                                       uint32_t& lohi, uint32_t& shv, float& lg) {
  K2 kt = tf(kca, kcb, 0u, (uint32_t)t);
  K2 kl = tf(kt.a, kt.b, 0u, 0u);
  K2 ka = tf(kt.a, kt.b, 0u, 1u);
  K2 kr = tf(kt.a, kt.b, 0u, 2u);
  K2 ku = tf(kt.a, kt.b, 0u, 3u);
  uint32_t l = 1u + ri_off(kl, 4095u);
  uint32_t a = ri_off(ka, 4097u - l);
  uint32_t b = a + l;
  uint32_t r = ri_off(kr, 4096u - l);
  uint32_t c = (b + r + 1u) % 4097u;
  uint32_t lo, hi, sh;
  if (a < c) { lo = a; hi = c; sh = b - a; }
  else       { lo = c; hi = b; sh = a - c; }
  uint32_t ub = xbits(ku);
  float uf = __uint_as_float((ub >> 9) | 0x3F800000u) - 1.0f;
  lohi = lo | (hi << 16);
  shv  = sh;
  lg   = (float)log((double)uf);
}

// smap: post-rotation source map (span = hi-lo).
__device__ __forceinline__ uint32_t smap2(uint32_t i, uint32_t lo, uint32_t span, uint32_t sh) {
  uint32_t t = i - lo;              // wraps huge if i < lo
  uint32_t u = t + sh;
  u = (u >= span) ? u - span : u;   // valid only when t < span
  return (t < span) ? lo + u : i;
}

// grid-parallel proposal precompute -> d_ws (16B records)
__global__ void prop_kernel(uint4* __restrict__ gprop) {
  int t = blockIdx.x * 256 + threadIdx.x;
  if (t >= TSTEPS) return;
  K2 kchain = tf(0u, 42u, 0u, 1u);
  uint32_t lohi, shv; float lg;
  make_prop(kchain.a, kchain.b, t, lohi, shv, lg);
  gprop[t] = make_uint4(lohi, shv, __float_as_uint(lg), 0u);
}

// raw barrier: NO vmcnt drain (keeps speculative global loads in flight)
#define SYNC() do { asm volatile("s_waitcnt lgkmcnt(0)" ::: "memory"); \
                    __builtin_amdgcn_s_barrier(); } while (0)

// f64 cross-lane via DPP on the two 32-bit halves (VALU pipe, no LDS).
template<int CTRL>
__device__ __forceinline__ double dpp_f64(double v) {
  long long s = __double_as_longlong(v);
  int lo = (int)(s & 0xFFFFFFFFll);
  int hi = (int)(s >> 32);
  lo = __builtin_amdgcn_update_dpp(0, lo, CTRL, 0xF, 0xF, true);
  hi = __builtin_amdgcn_update_dpp(0, hi, CTRL, 0xF, 0xF, true);
  return __longlong_as_double((long long)(unsigned)lo | ((long long)hi << 32));
}

__device__ __forceinline__ uint32_t rlu(uint32_t v, int l) {
  return (uint32_t)__builtin_amdgcn_readlane((int)v, l);
}

// compose through accepted-move stack (newest first), cost ∝ jc (uniform switch).
__device__ __forceinline__ uint32_t compose_sw(uint32_t pos, int jc,
                                               const uint32_t (&mlh)[12],
                                               const uint32_t (&msh)[12]) {
  switch (jc) {
    case 11: pos = smap2(pos, mlh[10] & 0xFFFFu, mlh[10] >> 16, msh[10]); [[fallthrough]];
    case 10: pos = smap2(pos, mlh[9]  & 0xFFFFu, mlh[9]  >> 16, msh[9]);  [[fallthrough]];
    case 9:  pos = smap2(pos, mlh[8]  & 0xFFFFu, mlh[8]  >> 16, msh[8]);  [[fallthrough]];
    case 8:  pos = smap2(pos, mlh[7]  & 0xFFFFu, mlh[7]  >> 16, msh[7]);  [[fallthrough]];
    case 7:  pos = smap2(pos, mlh[6]  & 0xFFFFu, mlh[6]  >> 16, msh[6]);  [[fallthrough]];
    case 6:  pos = smap2(pos, mlh[5]  & 0xFFFFu, mlh[5]  >> 16, msh[5]);  [[fallthrough]];
    case 5:  pos = smap2(pos, mlh[4]  & 0xFFFFu, mlh[4]  >> 16, msh[4]);  [[fallthrough]];
    case 4:  pos = smap2(pos, mlh[3]  & 0xFFFFu, mlh[3]  >> 16, msh[3]);  [[fallthrough]];
    case 3:  pos = smap2(pos, mlh[2]  & 0xFFFFu, mlh[2]  >> 16, msh[2]);  [[fallthrough]];
    case 2:  pos = smap2(pos, mlh[1]  & 0xFFFFu, mlh[1]  >> 16, msh[1]);  [[fallthrough]];
    case 1:  pos = smap2(pos, mlh[0]  & 0xFFFFu, mlh[0]  >> 16, msh[0]);  break;
    default: break;
  }
  return pos;
}

// materialize new base = old base ∘ stack (params from LDS, uniform); emit row.
__device__ __forceinline__ void mat_emit(int tid, int jcu, uint32_t cur,
                                         const uint32_t* __restrict__ s_mvlh,
                                         const uint32_t* __restrict__ s_mvsh,
                                         uint32_t (*s_base)[NW],
                                         bool emit, int row, int* __restrict__ out) {
  uint32_t posa[16];
  #pragma unroll
  for (int k = 0; k < 16; ++k) posa[k] = (uint32_t)tid + (uint32_t)k * 256u;
  for (int j = jcu - 1; j >= 0; --j) {        // scalar loop, newest first
    uint32_t lh = s_mvlh[j], sh = s_mvsh[j];  // uniform LDS broadcast
    uint32_t lo = lh & 0xFFFFu, sp = lh >> 16;
    #pragma unroll
    for (int k = 0; k < 16; ++k) posa[k] = smap2(posa[k], lo, sp, sh);
  }
  uint32_t vals[16];
  #pragma unroll
  for (int k = 0; k < 16; ++k) vals[k] = s_base[cur][posa[k]];
  #pragma unroll
  for (int k = 0; k < 16; ++k) {
    uint32_t i = (uint32_t)tid + (uint32_t)k * 256u;
    s_base[cur ^ 1u][i] = vals[k];
    if (emit) out[(size_t)row * NW + i] = (int)vals[k];
  }
}

// one MCMC step on wave 0. k = step index within window (RUNTIME, uniform).
// Proposal slots come from the lane-batched registers via SGPR-index readlane.
// Consumes ld (issued 2 steps ago), refills it for step k+2. Barrier-free.
__device__ __forceinline__ void stepf(
    int k, uint32_t lane, float sgn, float& ld, bool& accp, int& jc,
    uint32_t (&mlh)[12], uint32_t (&msh)[12],
    uint32_t cAlh, uint32_t cAsh, float cAlg,
    const uint32_t* __restrict__ sbase,
    uint32_t* __restrict__ s_mvlh, uint32_t* __restrict__ s_mvsh,
    const float* __restrict__ bigram, const float* __restrict__ startw,
    const float* __restrict__ endw,
    uint32_t rsrc, uint32_t csrc, bool isload, uint32_t base8) {

  uint32_t p = lane & 7u;
  uint32_t vset = (lane >> 3) & 3u;   // 0=RR 1=RA(S_{T+1}) 2=AR(S_T) 3=AA

  // proposal slots (SGPR-index readlane -> SGPRs; position math on SALU)
  uint32_t s0lh = rlu(cAlh, k);
  uint32_t s0sh = rlu(cAsh, k);
  float    s0lg = __uint_as_float(rlu(__float_as_uint(cAlg), k));
  uint32_t s1lh = rlu(cAlh, k + 1);
  uint32_t s1sh = rlu(cAsh, k + 1);
  uint32_t s2lh = rlu(cAlh, k + 2);
  uint32_t s2sh = rlu(cAsh, k + 2);

  // positions g from proposal T+2
  uint32_t lo2 = s2lh & 0xFFFFu, hi2 = s2lh >> 16, sh2 = s2sh;
  uint32_t g0 = lo2, g1 = lo2 + sh2, g2v = g1 - 1u, g3 = hi2 - 1u;
  uint32_t g4 = (lo2 > 0u) ? lo2 - 1u : 0u;
  uint32_t g5 = (hi2 < (uint32_t)NW) ? hi2 : 0u;
  uint32_t pos = (p == 0u) ? g0 : (p == 1u) ? g1 : (p == 2u) ? g2v
               : (p == 3u) ? g3 : (p == 4u) ? g4 : g5;

  uint32_t lo1 = s1lh & 0xFFFFu, sp1 = (s1lh >> 16) - lo1, sh1 = s1sh;
  uint32_t lo0 = s0lh & 0xFFFFu, sp0 = (s0lh >> 16) - lo0, sh0 = s0sh;
  if (vset & 1u) pos = smap2(pos, lo1, sp1, sh1);
  if (vset & 2u) pos = smap2(pos, lo0, sp0, sh0);
  pos = compose_sw(pos, jc, mlh, msh);
  uint32_t val = sbase[pos];                    // one ds_read, 32 lanes

  // ---- decision for T: DPP reduction (VALU pipe only) ----
  // row_shr accumulates at HIGH lanes: lane7 = d_R, lane15 = d_A.
  double du = (double)(ld * sgn);
  du += dpp_f64<0x111>(du);            // row_shr:1
  du += dpp_f64<0x112>(du);            // row_shr:2
  du += dpp_f64<0x114>(du);            // row_shr:4
  double dmin = du < 0.0 ? du : 0.0;
  int accl = (dmin > (double)s0lg) ? 1 : 0;
  int accR = __builtin_amdgcn_readlane(accl, 7);
  int accA = __builtin_amdgcn_readlane(accl, 15);
  int acc = accp ? accA : accR;                 // scalar, uniform

  // ---- row/col with accept-select folded into the shuffle index ----
  uint32_t selb = (uint32_t)acc * 16u + base8;
  uint32_t row = (uint32_t)__shfl((int)val, (int)(selb + rsrc), 64);
  uint32_t col = (uint32_t)__shfl((int)val, (int)(selb + csrc), 64);
  bool isbi = (p < 2u) || ((p < 4u) ? (lo2 > 0u) : (hi2 < (uint32_t)NW));
  const float* addr = isbi ? (bigram + (size_t)row * NW + col)
                           : ((p < 4u) ? (startw + col) : (endw + row));
  if (isload) ld = *addr;

  // ---- bookkeeping (acc scalar => uniform branches; static stack indices) ----
  if (acc) {
    uint32_t nv = lo0 | (sp0 << 16);
    switch (jc) {
      case 0:  mlh[0]  = nv; msh[0]  = sh0; break;
      case 1:  mlh[1]  = nv; msh[1]  = sh0; break;
      case 2:  mlh[2]  = nv; msh[2]  = sh0; break;
      case 3:  mlh[3]  = nv; msh[3]  = sh0; break;
      case 4:  mlh[4]  = nv; msh[4]  = sh0; break;
      case 5:  mlh[5]  = nv; msh[5]  = sh0; break;
      case 6:  mlh[6]  = nv; msh[6]  = sh0; break;
      case 7:  mlh[7]  = nv; msh[7]  = sh0; break;
      case 8:  mlh[8]  = nv; msh[8]  = sh0; break;
      case 9:  mlh[9]  = nv; msh[9]  = sh0; break;
      case 10: mlh[10] = nv; msh[10] = sh0; break;
      default: break;
    }
    if (lane == 0u) { s_mvlh[jc] = nv; s_mvsh[jc] = sh0; }
    jc++;
  }
  accp = (acc != 0);
}

__global__ __launch_bounds__(NTHR)
void TwoOptMCMC_86148454023515_kernel(const float* __restrict__ bigram,
                                      const float* __restrict__ startw,
                                      const float* __restrict__ endw,
                                      int* __restrict__ out,
                                      const uint4* __restrict__ gprop) {
  __shared__ __align__(16) uint32_t s_base[2][NW];   // 32 KB ping-pong; aliased for init sort
  __shared__ uint32_t s_mvlh[12];
  __shared__ uint32_t s_mvsh[12];
  __shared__ uint32_t s_jc[1];

  unsigned long long* s_comp = (unsigned long long*)s_base;
  const int tid = threadIdx.x;
  K2 kinit  = tf(0u, 42u, 0u, 0u);
  K2 kchain = tf(0u, 42u, 0u, 1u);

  // ---- initial permutation: 2-round stable-sort shuffle ----
  {
    K2 kc = kinit;
    for (int rnd = 0; rnd < 2; ++rnd) {
      K2 knext = tf(kc.a, kc.b, 0u, 0u);
      K2 ksub  = tf(kc.a, kc.b, 0u, 1u);
      for (int i = tid; i < NW; i += NTHR) {
        K2 r = tf(ksub.a, ksub.b, 0u, (uint32_t)i);
        uint32_t sk = r.a ^ r.b;
        unsigned long long pv = (rnd == 0) ? (unsigned long long)(uint32_t)i
                                           : (s_comp[i] & 0xFFFull);
        s_comp[i] = ((unsigned long long)sk << 24) |
                    ((unsigned long long)(uint32_t)i << 12) | pv;
      }
      __syncthreads();
      for (int k = 2; k <= NW; k <<= 1) {
        for (int j = k >> 1; j > 0; j >>= 1) {
          for (int i = tid; i < NW; i += NTHR) {
            int ixj = i ^ j;
            if (ixj > i) {
              unsigned long long va = s_comp[i], vb = s_comp[ixj];
              bool up = ((i & k) == 0);
              if ((va > vb) == up) { s_comp[i] = vb; s_comp[ixj] = va; }
            }
          }
          __syncthreads();
        }
      }
      kc = knext;
    }
    uint32_t pv[16];
    #pragma unroll
    for (int k = 0; k < 16; ++k) pv[k] = (uint32_t)(s_comp[tid + k * 256] & 0xFFFull);
    __syncthreads();
    #pragma unroll
    for (int k = 0; k < 16; ++k) s_base[0][tid + k * 256] = pv[k];
    __syncthreads();
  }

  const int wave = tid >> 6;
  const uint32_t lane = (uint32_t)(tid & 63);

  if (wave == 0) {
    // ---- wave 0: barrier-free MCMC windows, lane-batched proposals ----
    uint32_t mlh[12], msh[12];
    #pragma unroll
    for (int k = 0; k < 12; ++k) { mlh[k] = 0u; msh[k] = 0u; }
    int jc = 0; bool accp = false; uint32_t cur = 0u;
    float ld0 = 0.f, ld1 = 0.f;

    uint32_t p = lane & 7u;
    uint32_t vset = (lane >> 3) & 3u;
    float sgn = (p >= 6u) ? 0.f : ((p & 1u) ? -1.f : 1.f);
    uint32_t rsrc = (p == 0u) ? 3u : (p == 1u) ? 2u : (p <= 3u) ? 4u : (p == 4u) ? 2u : 3u;
    uint32_t csrc = (p == 0u) ? 0u : (p <= 2u) ? 1u : (p == 3u) ? 0u : 5u;
    bool isload = (vset < 2u) && (p < 6u);
    uint32_t base8 = lane & ~7u;

    // batch for window 0 (lane i = proposal i, i<14)
    uint32_t cAlh, cAsh; float cAlg;
    {
      int idx = (int)(lane < 14u ? lane : 13u);
      if (gprop) { uint4 gp = gprop[idx]; cAlh = gp.x; cAsh = gp.y; cAlg = __uint_as_float(gp.z); }
      else       { make_prop(kchain.a, kchain.b, idx, cAlh, cAsh, cAlg); }
    }

    // prologue A: loads for t=0, direct from P_0 -> ld0
    {
      uint32_t s0lh = rlu(cAlh, 0);
      uint32_t s0sh = rlu(cAsh, 0);
      uint32_t lo2 = s0lh & 0xFFFFu, hi2 = s0lh >> 16, sh2 = s0sh;
      uint32_t g0 = lo2, g1 = lo2 + sh2, g2v = g1 - 1u, g3 = hi2 - 1u;
      uint32_t g4 = (lo2 > 0u) ? lo2 - 1u : 0u;
      uint32_t g5 = (hi2 < (uint32_t)NW) ? hi2 : 0u;
      uint32_t pos = (p == 0u) ? g0 : (p == 1u) ? g1 : (p == 2u) ? g2v
                   : (p == 3u) ? g3 : (p == 4u) ? g4 : g5;
      uint32_t val = s_base[0][pos];
      uint32_t row = (uint32_t)__shfl((int)val, (int)(base8 + rsrc), 64);
      uint32_t col = (uint32_t)__shfl((int)val, (int)(base8 + csrc), 64);
      bool isbi = (p < 2u) || ((p < 4u) ? (lo2 > 0u) : (hi2 < (uint32_t)NW));
      const float* addr = isbi ? (bigram + (size_t)row * NW + col)
                               : ((p < 4u) ? (startw + col) : (endw + row));
      if (isload) ld0 = *addr;
    }
    // prologue B: loads for t=1; vset&1 composes S_0 -> ld1
    {
      uint32_t s0lh = rlu(cAlh, 0);
      uint32_t s0sh = rlu(cAsh, 0);
      uint32_t s1lh = rlu(cAlh, 1);
      uint32_t s1sh = rlu(cAsh, 1);
      uint32_t lo2 = s1lh & 0xFFFFu, hi2 = s1lh >> 16, sh2 = s1sh;
      uint32_t g0 = lo2, g1 = lo2 + sh2, g2v = g1 - 1u, g3 = hi2 - 1u;
      uint32_t g4 = (lo2 > 0u) ? lo2 - 1u : 0u;
      uint32_t g5 = (hi2 < (uint32_t)NW) ? hi2 : 0u;
      uint32_t pos = (p == 0u) ? g0 : (p == 1u) ? g1 : (p == 2u) ? g2v
                   : (p == 3u) ? g3 : (p == 4u) ? g4 : g5;
      uint32_t lo0 = s0lh & 0xFFFFu, sp0 = (s0lh >> 16) - lo0, sh0 = s0sh;
      if (vset & 1u) pos = smap2(pos, lo0, sp0, sh0);
      uint32_t val = s_base[0][pos];
      uint32_t row = (uint32_t)__shfl((int)val, (int)(base8 + rsrc), 64);
      uint32_t col = (uint32_t)__shfl((int)val, (int)(base8 + csrc), 64);
      bool isbi = (p < 2u) || ((p < 4u) ? (lo2 > 0u) : (hi2 < (uint32_t)NW));
      const float* addr = isbi ? (bigram + (size_t)row * NW + col)
                               : ((p < 4u) ? (startw + col) : (endw + row));
      if (isload) ld1 = *addr;
    }

    int t = 0;
    for (int b = 0; b < NBOUND; ++b) {
      int wlen = (b < 10) ? 10 : ((b == 10) ? 1 : 11);
      int t_next = t + wlen;

      // prefetch next window's batch (first use ~wlen steps away)
      uint32_t nlh, nsh; float nlg;
      {
        int idx = t_next + (int)(lane < 14u ? lane : 13u);
        if (idx > TSTEPS - 1) idx = TSTEPS - 1;
        if (gprop) { uint4 gp = gprop[idx]; nlh = gp.x; nsh = gp.y; nlg = __uint_as_float(gp.z); }
        else       { make_prop(kchain.a, kchain.b, idx, nlh, nsh, nlg); }
      }

      const uint32_t* sb = s_base[cur];
      // runtime-k window loop (small I$ footprint; one stepf body)
      #pragma unroll 1
      for (int k = 0; k < wlen; ++k) {
        stepf(k, lane, sgn, ld0, accp, jc, mlh, msh, cAlh, cAsh, cAlg,
              sb, s_mvlh, s_mvsh, bigram, startw, endw,
              rsrc, csrc, isload, base8);
        float tmp = ld0; ld0 = ld1; ld1 = tmp;   // alternate 2-deep buffers
      }

      if (lane == 0u) s_jc[0] = (uint32_t)jc;
      SYNC();                                       // publish move list
      mat_emit(tid, jc, cur, s_mvlh, s_mvsh, s_base, b >= 10, b - 10, out);
      SYNC();                                       // new base complete
      // parity handled by the per-step swap (wlen swaps total), matching R11
      cAlh = nlh; cAsh = nsh; cAlg = nlg;
      jc = 0; cur ^= 1u; t = t_next;
    }
  } else {
    // ---- waves 1-3: parked; materialize + emit at each boundary ----
    for (int b = 0; b < NBOUND; ++b) {
      SYNC();
      int jcu = __builtin_amdgcn_readfirstlane((int)s_jc[0]);
      mat_emit(tid, jcu, (uint32_t)(b & 1), s_mvlh, s_mvsh, s_base, b >= 10, b - 10, out);
      SYNC();
    }
  }
}

extern "C" void kernel_launch(void* const* d_in, const int* in_sizes, int n_in,
                              void* d_out, int out_size, void* d_ws, size_t ws_size,
                              hipStream_t stream) {
  (void)in_sizes; (void)n_in; (void)out_size;
  const float* bigram = (const float*)d_in[1];
  const float* startw = (const float*)d_in[2];
  const float* endw   = (const float*)d_in[3];
  int* out = (int*)d_out;
  uint4* gprop = nullptr;
  if (ws_size >= (size_t)TSTEPS * 16) {
    gprop = (uint4*)d_ws;
    hipLaunchKernelGGL(prop_kernel, dim3((TSTEPS + 255) / 256), dim3(256), 0, stream, gprop);
  }
  hipLaunchKernelGGL(TwoOptMCMC_86148454023515_kernel, dim3(1), dim3(NTHR), 0, stream,
                     bigram, startw, endw, out, gprop);
}

// Round 17
// 4595.411 us; speedup vs baseline: 1.3500x; 1.3500x over previous
//
#include <hip/hip_runtime.h>
#include <stdint.h>
#include <math.h>

#define NW      4096
#define TSTEPS  5722     // BURNIN + (512-1)*11 + 1
#define BURN    100
#define SSTRIDE 11
#define NTHR    256
#define NBOUND  522      // 10 windows(10) + 1 window(1 @t=100) + 511 windows(11)

struct K2 { uint32_t a, b; };

// Threefry-2x32, 20 rounds — matches jax._src.prng.threefry2x32 exactly.
__device__ __forceinline__ K2 tf(uint32_t k0, uint32_t k1, uint32_t c0, uint32_t c1) {
  uint32_t ks2 = k0 ^ k1 ^ 0x1BD11BDAu;
  uint32_t x0 = c0 + k0, x1 = c1 + k1;
#define RR(r) { x0 += x1; x1 = (x1 << (r)) | (x1 >> (32 - (r))); x1 ^= x0; }
  RR(13) RR(15) RR(26) RR(6)
  x0 += k1;  x1 += ks2 + 1u;
  RR(17) RR(29) RR(16) RR(24)
  x0 += ks2; x1 += k0 + 2u;
  RR(13) RR(15) RR(26) RR(6)
  x0 += k0;  x1 += k1 + 3u;
  RR(17) RR(29) RR(16) RR(24)
  x0 += k1;  x1 += ks2 + 4u;
  RR(13) RR(15) RR(26) RR(6)
  x0 += ks2; x1 += k0 + 5u;
#undef RR
  K2 r; r.a = x0; r.b = x1; return r;
}

__device__ __forceinline__ uint32_t xbits(K2 k) {
  K2 r = tf(k.a, k.b, 0u, 0u);
  return r.a ^ r.b;
}

__device__ __forceinline__ uint32_t ri_off(K2 key, uint32_t span) {
  K2 k1 = tf(key.a, key.b, 0u, 0u);
  K2 k2 = tf(key.a, key.b, 0u, 1u);
  uint32_t hb = xbits(k1);
  uint32_t lb = xbits(k2);
  uint32_t m = 65536u % span;
  m = (m * m) % span;
  return ((hb % span) * m + (lb % span)) % span;
}

__device__ __noinline__ void make_prop(uint32_t kca, uint32_t kcb, int t,
                                       uint32_t& lohi, uint32_t& shv, float& lg) {
  K2 kt = tf(kca, kcb, 0u, (uint32_t)t);
  K2 kl = tf(kt.a, kt.b, 0u, 0u);
  K2 ka = tf(kt.a, kt.b, 0u, 1u);
  K2 kr = tf(kt.a, kt.b, 0u, 2u);
  K2 ku = tf(kt.a, kt.b, 0u, 3u);
  uint32_t l = 1u + ri_off(kl, 4095u);
  uint32_t a = ri_off(ka, 4097u - l);
  uint32_t b = a + l;
  uint32_t r = ri_off(kr, 4096u - l);
  uint32_t c = (b + r + 1u) % 4097u;
  uint32_t lo, hi, sh;
  if (a < c) { lo = a; hi = c; sh = b - a; }
  else       { lo = c; hi = b; sh = a - c; }
  uint32_t ub = xbits(ku);
  float uf = __uint_as_float((ub >> 9) | 0x3F800000u) - 1.0f;
  lohi = lo | (hi << 16);
  shv  = sh;
  lg   = (float)log((double)uf);
}

// smap: post-rotation source map (span = hi-lo).
__device__ __forceinline__ uint32_t smap2(uint32_t i, uint32_t lo, uint32_t span, uint32_t sh) {
  uint32_t t = i - lo;              // wraps huge if i < lo
  uint32_t u = t + sh;
  u = (u >= span) ? u - span : u;   // valid only when t < span
  return (t < span) ? lo + u : i;
}

// grid-parallel proposal precompute -> d_ws (16B records)
__global__ void prop_kernel(uint4* __restrict__ gprop) {
  int t = blockIdx.x * 256 + threadIdx.x;
  if (t >= TSTEPS) return;
  K2 kchain = tf(0u, 42u, 0u, 1u);
  uint32_t lohi, shv; float lg;
  make_prop(kchain.a, kchain.b, t, lohi, shv, lg);
  gprop[t] = make_uint4(lohi, shv, __float_as_uint(lg), 0u);
}

// raw barrier: NO vmcnt drain (keeps speculative global loads in flight)
#define SYNC() do { asm volatile("s_waitcnt lgkmcnt(0)" ::: "memory"); \
                    __builtin_amdgcn_s_barrier(); } while (0)

// f64 cross-lane via DPP on the two 32-bit halves (VALU pipe, no LDS).
template<int CTRL>
__device__ __forceinline__ double dpp_f64(double v) {
  long long s = __double_as_longlong(v);
  int lo = (int)(s & 0xFFFFFFFFll);
  int hi = (int)(s >> 32);
  lo = __builtin_amdgcn_update_dpp(0, lo, CTRL, 0xF, 0xF, true);
  hi = __builtin_amdgcn_update_dpp(0, hi, CTRL, 0xF, 0xF, true);
  return __longlong_as_double((long long)(unsigned)lo | ((long long)hi << 32));
}

// compose through accepted-move stack (newest first), cost ∝ jc (uniform switch).
__device__ __forceinline__ uint32_t compose_sw(uint32_t pos, int jc,
                                               const uint32_t (&mlh)[12],
                                               const uint32_t (&msh)[12]) {
  switch (jc) {
    case 11: pos = smap2(pos, mlh[10] & 0xFFFFu, mlh[10] >> 16, msh[10]); [[fallthrough]];
    case 10: pos = smap2(pos, mlh[9]  & 0xFFFFu, mlh[9]  >> 16, msh[9]);  [[fallthrough]];
    case 9:  pos = smap2(pos, mlh[8]  & 0xFFFFu, mlh[8]  >> 16, msh[8]);  [[fallthrough]];
    case 8:  pos = smap2(pos, mlh[7]  & 0xFFFFu, mlh[7]  >> 16, msh[7]);  [[fallthrough]];
    case 7:  pos = smap2(pos, mlh[6]  & 0xFFFFu, mlh[6]  >> 16, msh[6]);  [[fallthrough]];
    case 6:  pos = smap2(pos, mlh[5]  & 0xFFFFu, mlh[5]  >> 16, msh[5]);  [[fallthrough]];
    case 5:  pos = smap2(pos, mlh[4]  & 0xFFFFu, mlh[4]  >> 16, msh[4]);  [[fallthrough]];
    case 4:  pos = smap2(pos, mlh[3]  & 0xFFFFu, mlh[3]  >> 16, msh[3]);  [[fallthrough]];
    case 3:  pos = smap2(pos, mlh[2]  & 0xFFFFu, mlh[2]  >> 16, msh[2]);  [[fallthrough]];
    case 2:  pos = smap2(pos, mlh[1]  & 0xFFFFu, mlh[1]  >> 16, msh[1]);  [[fallthrough]];
    case 1:  pos = smap2(pos, mlh[0]  & 0xFFFFu, mlh[0]  >> 16, msh[0]);  break;
    default: break;
  }
  return pos;
}

// materialize new base = old base ∘ stack (params from LDS, uniform); emit row.
__device__ __forceinline__ void mat_emit(int tid, int jcu, uint32_t cur,
                                         const uint32_t* __restrict__ s_mvlh,
                                         const uint32_t* __restrict__ s_mvsh,
                                         uint32_t (*s_base)[NW],
                                         bool emit, int row, int* __restrict__ out) {
  uint32_t posa[16];
  #pragma unroll
  for (int k = 0; k < 16; ++k) posa[k] = (uint32_t)tid + (uint32_t)k * 256u;
  for (int j = jcu - 1; j >= 0; --j) {        // scalar loop, newest first
    uint32_t lh = s_mvlh[j], sh = s_mvsh[j];  // uniform LDS broadcast
    uint32_t lo = lh & 0xFFFFu, sp = lh >> 16;
    #pragma unroll
    for (int k = 0; k < 16; ++k) posa[k] = smap2(posa[k], lo, sp, sh);
  }
  uint32_t vals[16];
  #pragma unroll
  for (int k = 0; k < 16; ++k) vals[k] = s_base[cur][posa[k]];
  #pragma unroll
  for (int k = 0; k < 16; ++k) {
    uint32_t i = (uint32_t)tid + (uint32_t)k * 256u;
    s_base[cur ^ 1u][i] = vals[k];
    if (emit) out[(size_t)row * NW + i] = (int)vals[k];
  }
}

// one MCMC step on wave 0. K = step index within window (compile-time).
// Proposal slots come from the lane-batched registers via constant readlane.
// Consumes ld (issued 2 steps ago), refills it for step K+2. Barrier-free.
template<int K>
__device__ __forceinline__ void stepf(
    uint32_t lane, float sgn, float& ld, bool& accp, int& jc,
    uint32_t (&mlh)[12], uint32_t (&msh)[12],
    uint32_t cAlh, uint32_t cAsh, float cAlg,
    const uint32_t* __restrict__ sbase,
    uint32_t* __restrict__ s_mvlh, uint32_t* __restrict__ s_mvsh,
    const float* __restrict__ bigram, const float* __restrict__ startw,
    const float* __restrict__ endw,
    uint32_t rsrc, uint32_t csrc, bool isload, uint32_t base8) {

  uint32_t p = lane & 7u;
  uint32_t vset = (lane >> 3) & 3u;   // 0=RR 1=RA(S_{T+1}) 2=AR(S_T) 3=AA

  // proposal slots (constant-index readlane -> SGPRs; position math on SALU)
  uint32_t s0lh = (uint32_t)__builtin_amdgcn_readlane((int)cAlh, K);
  uint32_t s0sh = (uint32_t)__builtin_amdgcn_readlane((int)cAsh, K);
  float    s0lg = __uint_as_float((uint32_t)__builtin_amdgcn_readlane(
                      (int)__float_as_uint(cAlg), K));
  uint32_t s1lh = (uint32_t)__builtin_amdgcn_readlane((int)cAlh, K + 1);
  uint32_t s1sh = (uint32_t)__builtin_amdgcn_readlane((int)cAsh, K + 1);
  uint32_t s2lh = (uint32_t)__builtin_amdgcn_readlane((int)cAlh, K + 2);
  uint32_t s2sh = (uint32_t)__builtin_amdgcn_readlane((int)cAsh, K + 2);

  // positions g from proposal T+2
  uint32_t lo2 = s2lh & 0xFFFFu, hi2 = s2lh >> 16, sh2 = s2sh;
  uint32_t g0 = lo2, g1 = lo2 + sh2, g2v = g1 - 1u, g3 = hi2 - 1u;
  uint32_t g4 = (lo2 > 0u) ? lo2 - 1u : 0u;
  uint32_t g5 = (hi2 < (uint32_t)NW) ? hi2 : 0u;
  uint32_t pos = (p == 0u) ? g0 : (p == 1u) ? g1 : (p == 2u) ? g2v
               : (p == 3u) ? g3 : (p == 4u) ? g4 : g5;

  uint32_t lo1 = s1lh & 0xFFFFu, sp1 = (s1lh >> 16) - lo1, sh1 = s1sh;
  uint32_t lo0 = s0lh & 0xFFFFu, sp0 = (s0lh >> 16) - lo0, sh0 = s0sh;
  if (vset & 1u) pos = smap2(pos, lo1, sp1, sh1);
  if (vset & 2u) pos = smap2(pos, lo0, sp0, sh0);
  pos = compose_sw(pos, jc, mlh, msh);
  uint32_t val = sbase[pos];                    // one ds_read, 32 lanes

  // ---- decision for T: DPP reduction (VALU pipe only) ----
  // row_shr accumulates at HIGH lanes: lane7 = d_R, lane15 = d_A.
  double du = (double)(ld * sgn);
  du += dpp_f64<0x111>(du);            // row_shr:1
  du += dpp_f64<0x112>(du);            // row_shr:2
  du += dpp_f64<0x114>(du);            // row_shr:4
  double dmin = du < 0.0 ? du : 0.0;
  int accl = (dmin > (double)s0lg) ? 1 : 0;
  int accR = __builtin_amdgcn_readlane(accl, 7);
  int accA = __builtin_amdgcn_readlane(accl, 15);
  int acc = accp ? accA : accR;                 // scalar, uniform

  // ---- row/col with accept-select folded into the shuffle index ----
  uint32_t selb = (uint32_t)acc * 16u + base8;
  uint32_t row = (uint32_t)__shfl((int)val, (int)(selb + rsrc), 64);
  uint32_t col = (uint32_t)__shfl((int)val, (int)(selb + csrc), 64);
  bool isbi = (p < 2u) || ((p < 4u) ? (lo2 > 0u) : (hi2 < (uint32_t)NW));
  const float* addr = isbi ? (bigram + (size_t)row * NW + col)
                           : ((p < 4u) ? (startw + col) : (endw + row));
  if (isload) ld = *addr;

  // ---- bookkeeping (acc scalar => uniform branches; static stack indices) ----
  if (acc) {
    uint32_t nv = lo0 | (sp0 << 16);
    switch (jc) {
      case 0:  mlh[0]  = nv; msh[0]  = sh0; break;
      case 1:  mlh[1]  = nv; msh[1]  = sh0; break;
      case 2:  mlh[2]  = nv; msh[2]  = sh0; break;
      case 3:  mlh[3]  = nv; msh[3]  = sh0; break;
      case 4:  mlh[4]  = nv; msh[4]  = sh0; break;
      case 5:  mlh[5]  = nv; msh[5]  = sh0; break;
      case 6:  mlh[6]  = nv; msh[6]  = sh0; break;
      case 7:  mlh[7]  = nv; msh[7]  = sh0; break;
      case 8:  mlh[8]  = nv; msh[8]  = sh0; break;
      case 9:  mlh[9]  = nv; msh[9]  = sh0; break;
      case 10: mlh[10] = nv; msh[10] = sh0; break;
      default: break;
    }
    if (lane == 0u) { s_mvlh[jc] = nv; s_mvsh[jc] = sh0; }
    jc++;
  }
  accp = (acc != 0);
}

__global__ __launch_bounds__(NTHR)
void TwoOptMCMC_86148454023515_kernel(const float* __restrict__ bigram,
                                      const float* __restrict__ startw,
                                      const float* __restrict__ endw,
                                      int* __restrict__ out,
                                      const uint4* __restrict__ gprop) {
  __shared__ __align__(16) uint32_t s_base[2][NW];   // 32 KB ping-pong; aliased for init sort
  __shared__ uint32_t s_mvlh[12];
  __shared__ uint32_t s_mvsh[12];
  __shared__ uint32_t s_jc[1];

  unsigned long long* s_comp = (unsigned long long*)s_base;
  const int tid = threadIdx.x;
  K2 kinit  = tf(0u, 42u, 0u, 0u);
  K2 kchain = tf(0u, 42u, 0u, 1u);

  // ---- initial permutation: 2-round stable-sort shuffle ----
  {
    K2 kc = kinit;
    for (int rnd = 0; rnd < 2; ++rnd) {
      K2 knext = tf(kc.a, kc.b, 0u, 0u);
      K2 ksub  = tf(kc.a, kc.b, 0u, 1u);
      for (int i = tid; i < NW; i += NTHR) {
        K2 r = tf(ksub.a, ksub.b, 0u, (uint32_t)i);
        uint32_t sk = r.a ^ r.b;
        unsigned long long pv = (rnd == 0) ? (unsigned long long)(uint32_t)i
                                           : (s_comp[i] & 0xFFFull);
        s_comp[i] = ((unsigned long long)sk << 24) |
                    ((unsigned long long)(uint32_t)i << 12) | pv;
      }
      __syncthreads();
      for (int k = 2; k <= NW; k <<= 1) {
        for (int j = k >> 1; j > 0; j >>= 1) {
          for (int i = tid; i < NW; i += NTHR) {
            int ixj = i ^ j;
            if (ixj > i) {
              unsigned long long va = s_comp[i], vb = s_comp[ixj];
              bool up = ((i & k) == 0);
              if ((va > vb) == up) { s_comp[i] = vb; s_comp[ixj] = va; }
            }
          }
          __syncthreads();
        }
      }
      kc = knext;
    }
    uint32_t pv[16];
    #pragma unroll
    for (int k = 0; k < 16; ++k) pv[k] = (uint32_t)(s_comp[tid + k * 256] & 0xFFFull);
    __syncthreads();
    #pragma unroll
    for (int k = 0; k < 16; ++k) s_base[0][tid + k * 256] = pv[k];
    __syncthreads();
  }

  const int wave = tid >> 6;
  const uint32_t lane = (uint32_t)(tid & 63);

  if (wave == 0) {
    // ---- wave 0: barrier-free MCMC windows, lane-batched proposals ----
    uint32_t mlh[12], msh[12];
    #pragma unroll
    for (int k = 0; k < 12; ++k) { mlh[k] = 0u; msh[k] = 0u; }
    int jc = 0; bool accp = false; uint32_t cur = 0u;
    float ldA = 0.f, ldB = 0.f;

    uint32_t p = lane & 7u;
    uint32_t vset = (lane >> 3) & 3u;
    float sgn = (p >= 6u) ? 0.f : ((p & 1u) ? -1.f : 1.f);
    uint32_t rsrc = (p == 0u) ? 3u : (p == 1u) ? 2u : (p <= 3u) ? 4u : (p == 4u) ? 2u : 3u;
    uint32_t csrc = (p == 0u) ? 0u : (p <= 2u) ? 1u : (p == 3u) ? 0u : 5u;
    bool isload = (vset < 2u) && (p < 6u);
    uint32_t base8 = lane & ~7u;

    // batch for window 0 (lane i = proposal i, i<14)
    uint32_t cAlh, cAsh; float cAlg;
    {
      int idx = (int)(lane < 14u ? lane : 13u);
      if (gprop) { uint4 gp = gprop[idx]; cAlh = gp.x; cAsh = gp.y; cAlg = __uint_as_float(gp.z); }
      else       { make_prop(kchain.a, kchain.b, idx, cAlh, cAsh, cAlg); }
    }

    // prologue A: loads for t=0, direct from P_0
    {
      uint32_t s0lh = (uint32_t)__builtin_amdgcn_readlane((int)cAlh, 0);
      uint32_t s0sh = (uint32_t)__builtin_amdgcn_readlane((int)cAsh, 0);
      uint32_t lo2 = s0lh & 0xFFFFu, hi2 = s0lh >> 16, sh2 = s0sh;
      uint32_t g0 = lo2, g1 = lo2 + sh2, g2v = g1 - 1u, g3 = hi2 - 1u;
      uint32_t g4 = (lo2 > 0u) ? lo2 - 1u : 0u;
      uint32_t g5 = (hi2 < (uint32_t)NW) ? hi2 : 0u;
      uint32_t pos = (p == 0u) ? g0 : (p == 1u) ? g1 : (p == 2u) ? g2v
                   : (p == 3u) ? g3 : (p == 4u) ? g4 : g5;
      uint32_t val = s_base[0][pos];
      uint32_t row = (uint32_t)__shfl((int)val, (int)(base8 + rsrc), 64);
      uint32_t col = (uint32_t)__shfl((int)val, (int)(base8 + csrc), 64);
      bool isbi = (p < 2u) || ((p < 4u) ? (lo2 > 0u) : (hi2 < (uint32_t)NW));
      const float* addr = isbi ? (bigram + (size_t)row * NW + col)
                               : ((p < 4u) ? (startw + col) : (endw + row));
      if (isload) ldA = *addr;
    }
    // prologue B: loads for t=1; vset&1 composes S_0
    {
      uint32_t s0lh = (uint32_t)__builtin_amdgcn_readlane((int)cAlh, 0);
      uint32_t s0sh = (uint32_t)__builtin_amdgcn_readlane((int)cAsh, 0);
      uint32_t s1lh = (uint32_t)__builtin_amdgcn_readlane((int)cAlh, 1);
      uint32_t s1sh = (uint32_t)__builtin_amdgcn_readlane((int)cAsh, 1);
      uint32_t lo2 = s1lh & 0xFFFFu, hi2 = s1lh >> 16, sh2 = s1sh;
      uint32_t g0 = lo2, g1 = lo2 + sh2, g2v = g1 - 1u, g3 = hi2 - 1u;
      uint32_t g4 = (lo2 > 0u) ? lo2 - 1u : 0u;
      uint32_t g5 = (hi2 < (uint32_t)NW) ? hi2 : 0u;
      uint32_t pos = (p == 0u) ? g0 : (p == 1u) ? g1 : (p == 2u) ? g2v
                   : (p == 3u) ? g3 : (p == 4u) ? g4 : g5;
      uint32_t lo0 = s0lh & 0xFFFFu, sp0 = (s0lh >> 16) - lo0, sh0 = s0sh;
      if (vset & 1u) pos = smap2(pos, lo0, sp0, sh0);
      uint32_t val = s_base[0][pos];
      uint32_t row = (uint32_t)__shfl((int)val, (int)(base8 + rsrc), 64);
      uint32_t col = (uint32_t)__shfl((int)val, (int)(base8 + csrc), 64);
      bool isbi = (p < 2u) || ((p < 4u) ? (lo2 > 0u) : (hi2 < (uint32_t)NW));
      const float* addr = isbi ? (bigram + (size_t)row * NW + col)
                               : ((p < 4u) ? (startw + col) : (endw + row));
      if (isload) ldB = *addr;
    }

#define STEPK(K, LD) stepf<K>(lane, sgn, LD, accp, jc, mlh, msh, cAlh, cAsh, cAlg, \
                              sb, s_mvlh, s_mvsh, bigram, startw, endw,            \
                              rsrc, csrc, isload, base8)

    int t = 0;
    for (int b = 0; b < NBOUND; ++b) {
      int wlen = (b < 10) ? 10 : ((b == 10) ? 1 : 11);
      int t_next = t + wlen;

      // prefetch next window's batch (first use ~wlen steps away)
      uint32_t nlh, nsh; float nlg;
      {
        int idx = t_next + (int)(lane < 14u ? lane : 13u);
        if (idx > TSTEPS - 1) idx = TSTEPS - 1;
        if (gprop) { uint4 gp = gprop[idx]; nlh = gp.x; nsh = gp.y; nlg = __uint_as_float(gp.z); }
        else       { make_prop(kchain.a, kchain.b, idx, nlh, nsh, nlg); }
      }

      const uint32_t* sb = s_base[cur];
      STEPK(0, ldA);
      if (wlen > 1) {
        STEPK(1, ldB); STEPK(2, ldA); STEPK(3, ldB); STEPK(4, ldA);
        STEPK(5, ldB); STEPK(6, ldA); STEPK(7, ldB); STEPK(8, ldA); STEPK(9, ldB);
      }
      if (wlen > 10) { STEPK(10, ldA); }

      if (lane == 0u) s_jc[0] = (uint32_t)jc;
      SYNC();                                       // publish move list
      mat_emit(tid, jc, cur, s_mvlh, s_mvsh, s_base, b >= 10, b - 10, out);
      SYNC();                                       // new base complete
      if (wlen & 1) { float tmp = ldA; ldA = ldB; ldB = tmp; }  // loads long done
      cAlh = nlh; cAsh = nsh; cAlg = nlg;
      jc = 0; cur ^= 1u; t = t_next;
    }
#undef STEPK
  } else {
    // ---- waves 1-3: parked; materialize + emit at each boundary ----
    for (int b = 0; b < NBOUND; ++b) {
      SYNC();
      int jcu = __builtin_amdgcn_readfirstlane((int)s_jc[0]);
      mat_emit(tid, jcu, (uint32_t)(b & 1), s_mvlh, s_mvsh, s_base, b >= 10, b - 10, out);
      SYNC();
    }
  }
}

extern "C" void kernel_launch(void* const* d_in, const int* in_sizes, int n_in,
                              void* d_out, int out_size, void* d_ws, size_t ws_size,
                              hipStream_t stream) {
  (void)in_sizes; (void)n_in; (void)out_size;
  const float* bigram = (const float*)d_in[1];
  const float* startw = (const float*)d_in[2];
  const float* endw   = (const float*)d_in[3];
  int* out = (int*)d_out;
  uint4* gprop = nullptr;
  if (ws_size >= (size_t)TSTEPS * 16) {
    gprop = (uint4*)d_ws;
    hipLaunchKernelGGL(prop_kernel, dim3((TSTEPS + 255) / 256), dim3(256), 0, stream, gprop);
  }
  hipLaunchKernelGGL(TwoOptMCMC_86148454023515_kernel, dim3(1), dim3(NTHR), 0, stream,
                     bigram, startw, endw, out, gprop);
}